// Round 1
// baseline (181.831 us; speedup 1.0000x reference)
//
#include <hip/hip_runtime.h>

#define B_ 128
#define O_ 1024
#define I_ 1024
#define EPS_ 1e-7f
#define NCHUNK 16
#define CI (I_ / NCHUNK)   // 64 i-values per block

// ---------------------------------------------------------------------------
// Kernel 1: build T[o,i] = (ix/iy + la)*(1+lm) - ox/oy, stored TRANSPOSED as
// Tt[i*O + o] so the main kernel reads the softmax axis (o) contiguously.
// 32x32 LDS tile transpose, block (32,8).
// ---------------------------------------------------------------------------
__global__ __launch_bounds__(256) void build_T_kernel(
    const float* __restrict__ ix, const float* __restrict__ iy,
    const float* __restrict__ ox, const float* __restrict__ oy,
    const float* __restrict__ la, const float* __restrict__ lm,
    float* __restrict__ Tt)
{
    __shared__ float tile[32][33];   // +1 pad: no bank conflicts
    const int i0 = blockIdx.x * 32;
    const int o0 = blockIdx.y * 32;
    const int tx = threadIdx.x;      // 0..31
    const int ty = threadIdx.y;      // 0..7

#pragma unroll
    for (int r = 0; r < 32; r += 8) {
        const int o = o0 + ty + r;
        const int i = i0 + tx;
        const int idx = o * I_ + i;                       // coalesced along i
        const float t = (ix[idx] / iy[idx] + la[idx]) * (1.0f + lm[idx])
                        - ox[idx] / oy[idx];
        tile[ty + r][tx] = t;        // tile[o_local][i_local]
    }
    __syncthreads();
#pragma unroll
    for (int r = 0; r < 32; r += 8) {
        const int i = i0 + ty + r;
        const int o = o0 + tx;
        Tt[i * O_ + o] = tile[tx][ty + r];                // coalesced along o
    }
}

// ---------------------------------------------------------------------------
// Kernel 2: one wave per (i-chunk, b). Each lane owns 16 o-values
// (o = 4*lane + 256*k + j). Per i: scores -> wave max -> exp -> wave sum ->
// accumulate d*w in registers. One atomicAdd pass per block at the end.
// ---------------------------------------------------------------------------
__global__ __launch_bounds__(64) void aeg_main_kernel(
    const float* __restrict__ data,   // (B, I)
    const float* __restrict__ Tt,     // (I, O) transposed T
    float* __restrict__ out)          // (B, O), pre-zeroed
{
    const int chunk = blockIdx.x;
    const int b     = blockIdx.y;
    const int lane  = threadIdx.x;    // 0..63

    const float* dptr = data + b * I_ + chunk * CI;

    float acc[16];
#pragma unroll
    for (int j = 0; j < 16; ++j) acc[j] = 0.0f;

    for (int ii = 0; ii < CI; ++ii) {
        const float dv   = dptr[ii];                       // wave-uniform load
        const float sig  = 1.0f / (1.0f + __expf(-dv));    // sigmoid(d)
        const float sig2 = sig * sig;

        const float4* row = (const float4*)(Tt + (size_t)(chunk * CI + ii) * O_);

        float s[16];
        float m = 0.0f;                                    // scores are > 0
#pragma unroll
        for (int k = 0; k < 4; ++k) {
            const float4 tv = row[lane + 64 * k];          // coalesced 16B/lane
            s[4 * k + 0] = rsqrtf(tv.x * tv.x * sig2 + EPS_);
            s[4 * k + 1] = rsqrtf(tv.y * tv.y * sig2 + EPS_);
            s[4 * k + 2] = rsqrtf(tv.z * tv.z * sig2 + EPS_);
            s[4 * k + 3] = rsqrtf(tv.w * tv.w * sig2 + EPS_);
            m = fmaxf(m, fmaxf(fmaxf(s[4 * k + 0], s[4 * k + 1]),
                               fmaxf(s[4 * k + 2], s[4 * k + 3])));
        }
        // wave-wide max over 64 lanes (scores reach rsqrt(eps)=3162 -> must
        // max-subtract or exp overflows)
#pragma unroll
        for (int off = 32; off > 0; off >>= 1)
            m = fmaxf(m, __shfl_xor(m, off));

        float e[16];
        float z = 0.0f;
#pragma unroll
        for (int j = 0; j < 16; ++j) {
            e[j] = __expf(s[j] - m);
            z += e[j];
        }
#pragma unroll
        for (int off = 32; off > 0; off >>= 1)
            z += __shfl_xor(z, off);

        const float scale = dv / z;                        // z >= 1 always
#pragma unroll
        for (int j = 0; j < 16; ++j) acc[j] += e[j] * scale;
    }

    float* ob = out + b * O_;
#pragma unroll
    for (int k = 0; k < 4; ++k) {
        const int o = 4 * lane + 256 * k;
        atomicAdd(&ob[o + 0], acc[4 * k + 0]);
        atomicAdd(&ob[o + 1], acc[4 * k + 1]);
        atomicAdd(&ob[o + 2], acc[4 * k + 2]);
        atomicAdd(&ob[o + 3], acc[4 * k + 3]);
    }
}

// ---------------------------------------------------------------------------
extern "C" void kernel_launch(void* const* d_in, const int* in_sizes, int n_in,
                              void* d_out, int out_size, void* d_ws, size_t ws_size,
                              hipStream_t stream)
{
    const float* data = (const float*)d_in[0];
    const float* ix   = (const float*)d_in[1];
    const float* iy   = (const float*)d_in[2];
    const float* ox   = (const float*)d_in[3];
    const float* oy   = (const float*)d_in[4];
    const float* la   = (const float*)d_in[5];
    const float* lm   = (const float*)d_in[6];
    float* out = (float*)d_out;
    float* Tt  = (float*)d_ws;     // O_*I_*4 = 4 MB scratch

    // d_out is poisoned to 0xAA before every timed call -> zero it (async,
    // graph-capture safe, stream-ordered before the atomics).
    hipMemsetAsync(d_out, 0, (size_t)B_ * O_ * sizeof(float), stream);

    build_T_kernel<<<dim3(I_ / 32, O_ / 32), dim3(32, 8), 0, stream>>>(
        ix, iy, ox, oy, la, lm, Tt);

    aeg_main_kernel<<<dim3(NCHUNK, B_), 64, 0, stream>>>(data, Tt, out);
}

// Round 2
// 150.951 us; speedup vs baseline: 1.2046x; 1.2046x over previous
//
#include <hip/hip_runtime.h>

#define B_ 128
#define O_ 1024
#define I_ 1024
#define EPS_ 1e-7f
#define NCHUNK 64
#define CI (I_ / NCHUNK)     // 16 i-values per wave
#define WPB 4                // waves per block
#define TT_BYTES ((size_t)O_ * I_ * sizeof(float))

// ---------------------------------------------------------------------------
// Kernel 1: Tt2[i*O + o] = T[o,i]^2  where T = (ix/iy + la)*(1+lm) - ox/oy.
// Stored transposed AND squared (main kernel only needs the square).
// ---------------------------------------------------------------------------
__global__ __launch_bounds__(256) void build_T2_kernel(
    const float* __restrict__ ix, const float* __restrict__ iy,
    const float* __restrict__ ox, const float* __restrict__ oy,
    const float* __restrict__ la, const float* __restrict__ lm,
    float* __restrict__ Tt2)
{
    __shared__ float tile[32][33];
    const int i0 = blockIdx.x * 32;
    const int o0 = blockIdx.y * 32;
    const int tx = threadIdx.x;      // 0..31
    const int ty = threadIdx.y;      // 0..7

#pragma unroll
    for (int r = 0; r < 32; r += 8) {
        const int o = o0 + ty + r;
        const int i = i0 + tx;
        const int idx = o * I_ + i;
        const float t = (ix[idx] / iy[idx] + la[idx]) * (1.0f + lm[idx])
                        - ox[idx] / oy[idx];
        tile[ty + r][tx] = t * t;
    }
    __syncthreads();
#pragma unroll
    for (int r = 0; r < 32; r += 8) {
        const int i = i0 + ty + r;
        const int o = o0 + tx;
        Tt2[i * O_ + o] = tile[tx][ty + r];
    }
}

// ---------------------------------------------------------------------------
// Kernel 1b: minr2[i] = min_o Tt2[i,o].  Because s = rsqrt(r2*sig2+eps) is
// monotone-decreasing in r2, the softmax max over o is rsqrt(minr2*sig2+eps)
// EXACTLY, for every b — so the main kernel needs no max-reduction.
// ---------------------------------------------------------------------------
__global__ __launch_bounds__(64) void min_row_kernel(
    const float* __restrict__ Tt2, float* __restrict__ minr2)
{
    const int i = blockIdx.x;
    const int lane = threadIdx.x;
    const float4* row = (const float4*)(Tt2 + (size_t)i * O_);
    float mn = 3.4e38f;
#pragma unroll
    for (int k = 0; k < 4; ++k) {
        const float4 v = row[lane + 64 * k];
        mn = fminf(mn, fminf(fminf(v.x, v.y), fminf(v.z, v.w)));
    }
#pragma unroll
    for (int off = 32; off > 0; off >>= 1)
        mn = fminf(mn, __shfl_xor(mn, off));
    if (lane == 0) minr2[i] = mn;
}

// ---------------------------------------------------------------------------
// Kernel 2: block = (chunk-group, b); 4 waves, wave w owns chunk
// blockIdx.x*4+w (16 i's). Lane owns 16 o's (o = 4*lane + 256*k + j).
// Per i: m from minr2 (no reduce), 16 rsqrt+exp, one 6-shfl sum reduce,
// register accumulate. Then LDS-reduce the 4 waves, 4 atomics/thread.
// ---------------------------------------------------------------------------
__global__ __launch_bounds__(256) void aeg_main_kernel(
    const float* __restrict__ data,   // (B, I)
    const float* __restrict__ Tt2,    // (I, O) transposed T^2
    const float* __restrict__ minr2,  // (I) or nullptr
    float* __restrict__ out)          // (B, O), pre-zeroed
{
    __shared__ float red[WPB][O_];    // 16 KB

    const int w    = threadIdx.x >> 6;
    const int lane = threadIdx.x & 63;
    const int chunk = blockIdx.x * WPB + w;
    const int b     = blockIdx.y;

    const float* dptr = data + b * I_ + chunk * CI;

    float acc[16];
#pragma unroll
    for (int j = 0; j < 16; ++j) acc[j] = 0.0f;

    for (int ii = 0; ii < CI; ++ii) {
        const int i = chunk * CI + ii;
        const float dv   = dptr[ii];
        const float sig  = 1.0f / (1.0f + __expf(-dv));
        const float sig2 = sig * sig;

        const float4* row = (const float4*)(Tt2 + (size_t)i * O_);
        float4 r[4];
#pragma unroll
        for (int k = 0; k < 4; ++k) r[k] = row[lane + 64 * k];

        float mr2;
        if (minr2) {
            mr2 = minr2[i];
        } else {
            float mn = 3.4e38f;
#pragma unroll
            for (int k = 0; k < 4; ++k)
                mn = fminf(mn, fminf(fminf(r[k].x, r[k].y), fminf(r[k].z, r[k].w)));
#pragma unroll
            for (int off = 32; off > 0; off >>= 1)
                mn = fminf(mn, __shfl_xor(mn, off));
            mr2 = mn;
        }
        const float m = rsqrtf(fmaf(mr2, sig2, EPS_));   // exact softmax max

        float e[16];
        float z = 0.0f;
#pragma unroll
        for (int k = 0; k < 4; ++k) {
            const float rr[4] = {r[k].x, r[k].y, r[k].z, r[k].w};
#pragma unroll
            for (int j = 0; j < 4; ++j) {
                const float s = rsqrtf(fmaf(rr[j], sig2, EPS_));
                const float ee = __expf(s - m);          // <= 1, no overflow
                e[4 * k + j] = ee;
                z += ee;
            }
        }
#pragma unroll
        for (int off = 32; off > 0; off >>= 1)
            z += __shfl_xor(z, off);

        const float scale = dv / z;                      // z >= 1
#pragma unroll
        for (int j = 0; j < 16; ++j) acc[j] = fmaf(e[j], scale, acc[j]);
    }

    // Stage per-wave accumulators and reduce across the 4 waves in LDS.
#pragma unroll
    for (int k = 0; k < 4; ++k) {
#pragma unroll
        for (int j = 0; j < 4; ++j)
            red[w][4 * lane + 256 * k + j] = acc[4 * k + j];
    }
    __syncthreads();

    const int t = threadIdx.x;       // 0..255, each sums 4 consecutive o's
    float4 v = ((const float4*)red[0])[t];
#pragma unroll
    for (int ww = 1; ww < WPB; ++ww) {
        const float4 u = ((const float4*)red[ww])[t];
        v.x += u.x; v.y += u.y; v.z += u.z; v.w += u.w;
    }
    float* ob = out + b * O_ + 4 * t;
    atomicAdd(&ob[0], v.x);
    atomicAdd(&ob[1], v.y);
    atomicAdd(&ob[2], v.z);
    atomicAdd(&ob[3], v.w);
}

// ---------------------------------------------------------------------------
extern "C" void kernel_launch(void* const* d_in, const int* in_sizes, int n_in,
                              void* d_out, int out_size, void* d_ws, size_t ws_size,
                              hipStream_t stream)
{
    const float* data = (const float*)d_in[0];
    const float* ix   = (const float*)d_in[1];
    const float* iy   = (const float*)d_in[2];
    const float* ox   = (const float*)d_in[3];
    const float* oy   = (const float*)d_in[4];
    const float* la   = (const float*)d_in[5];
    const float* lm   = (const float*)d_in[6];
    float* out  = (float*)d_out;
    float* Tt2  = (float*)d_ws;
    // minr2 lives right after Tt2 if the workspace is big enough; otherwise
    // the main kernel falls back to an in-wave min reduce (host-side branch
    // is deterministic across calls -> graph-capture safe).
    float* minr2 = (ws_size >= TT_BYTES + I_ * sizeof(float))
                       ? (float*)((char*)d_ws + TT_BYTES) : nullptr;

    hipMemsetAsync(d_out, 0, (size_t)B_ * O_ * sizeof(float), stream);

    build_T2_kernel<<<dim3(I_ / 32, O_ / 32), dim3(32, 8), 0, stream>>>(
        ix, iy, ox, oy, la, lm, Tt2);

    if (minr2)
        min_row_kernel<<<I_, 64, 0, stream>>>(Tt2, minr2);

    aeg_main_kernel<<<dim3(NCHUNK / WPB, B_), 256, 0, stream>>>(
        data, Tt2, minr2, out);
}

// Round 3
// 129.185 us; speedup vs baseline: 1.4075x; 1.1685x over previous
//
#include <hip/hip_runtime.h>

#define B_ 128
#define O_ 1024
#define I_ 1024
#define NCHUNK 64
#define CI (I_ / NCHUNK)     // 16 i-values per wave
#define WPB 4                // waves per block
#define TT_BYTES ((size_t)O_ * I_ * sizeof(float))

#define LOG2E_F  1.4426950408889634f
#define LN2_F    0.6931471805599453f
#define LN2SQ_F  0.4804530139182014f          // ln2^2
#define EPSC_F   (1e-7f * LN2SQ_F)            // eps * ln2^2

// Fast HW intrinsics (single v_rsq/v_exp/v_rcp, ~1e-7 rel err — absmax
// threshold has 9x headroom; libm versions expand to NR-refined sequences).
__device__ __forceinline__ float fast_rsq(float x)  { return __builtin_amdgcn_rsqf(x); }
__device__ __forceinline__ float fast_exp2(float x) { return __builtin_amdgcn_exp2f(x); }
__device__ __forceinline__ float fast_rcp(float x)  { return __builtin_amdgcn_rcpf(x); }

// ---------------------------------------------------------------------------
// Kernel 1: Tt2[i*O + o] = T[o,i]^2, T = (ix/iy + la)*(1+lm) - ox/oy.
// Transposed + squared (main kernel only needs the square, o-contiguous).
// ---------------------------------------------------------------------------
__global__ __launch_bounds__(256) void build_T2_kernel(
    const float* __restrict__ ix, const float* __restrict__ iy,
    const float* __restrict__ ox, const float* __restrict__ oy,
    const float* __restrict__ la, const float* __restrict__ lm,
    float* __restrict__ Tt2)
{
    __shared__ float tile[32][33];
    const int i0 = blockIdx.x * 32;
    const int o0 = blockIdx.y * 32;
    const int tx = threadIdx.x;      // 0..31
    const int ty = threadIdx.y;      // 0..7

#pragma unroll
    for (int r = 0; r < 32; r += 8) {
        const int o = o0 + ty + r;
        const int i = i0 + tx;
        const int idx = o * I_ + i;
        const float t = fmaf(ix[idx] * fast_rcp(iy[idx]) + la[idx],
                             1.0f + lm[idx],
                             -(ox[idx] * fast_rcp(oy[idx])));
        tile[ty + r][tx] = t * t;
    }
    __syncthreads();
#pragma unroll
    for (int r = 0; r < 32; r += 8) {
        const int i = i0 + ty + r;
        const int o = o0 + tx;
        Tt2[i * O_ + o] = tile[tx][ty + r];
    }
}

// ---------------------------------------------------------------------------
// Kernel 1b: minr2[i] = min_o Tt2[i,o].  s = rsqrt(r2*g+eps) is monotone
// decreasing in r2, so the softmax max over o is rsqrt(minr2*g+eps) EXACTLY
// for every b — main kernel needs no per-i max reduction.
// ---------------------------------------------------------------------------
__global__ __launch_bounds__(64) void min_row_kernel(
    const float* __restrict__ Tt2, float* __restrict__ minr2)
{
    const int i = blockIdx.x;
    const int lane = threadIdx.x;
    const float4* row = (const float4*)(Tt2 + (size_t)i * O_);
    float mn = 3.4e38f;
#pragma unroll
    for (int k = 0; k < 4; ++k) {
        const float4 v = row[lane + 64 * k];
        mn = fminf(mn, fminf(fminf(v.x, v.y), fminf(v.z, v.w)));
    }
#pragma unroll
    for (int off = 32; off > 0; off >>= 1)
        mn = fminf(mn, __shfl_xor(mn, off));
    if (lane == 0) minr2[i] = mn;
}

// ---------------------------------------------------------------------------
// Kernel 2: block = (chunk-group, b); 4 waves, wave w owns chunk
// blockIdx.x*4+w (16 i's). Lane owns 16 o's (o = 4*lane + 256*k + j).
// log2e folded into rsqrt arg: w ∝ exp2(rsqrt(r2*sig2c + epsc)), where
// sig2c = (sig*ln2)^2 — inner loop is exactly fma,rsq,sub,exp,add,fma.
// Row loads software-pipelined (prefetch i+1 while computing i).
// ---------------------------------------------------------------------------
__global__ __launch_bounds__(256) void aeg_main_kernel(
    const float* __restrict__ data,   // (B, I)
    const float* __restrict__ Tt2,    // (I, O) transposed T^2
    const float* __restrict__ minr2,  // (I) or nullptr
    float* __restrict__ out)          // (B, O), pre-zeroed
{
    __shared__ float red[WPB][O_];    // 16 KB

    const int w    = threadIdx.x >> 6;
    const int lane = threadIdx.x & 63;
    const int chunk = blockIdx.x * WPB + w;
    const int b     = blockIdx.y;

    const float* dptr = data + b * I_ + chunk * CI;
    const float4* rowbase = (const float4*)(Tt2 + (size_t)chunk * CI * O_);

    float acc[16];
#pragma unroll
    for (int j = 0; j < 16; ++j) acc[j] = 0.0f;

    // prefetch i = 0 row fragment
    float4 r[4];
#pragma unroll
    for (int k = 0; k < 4; ++k) r[k] = rowbase[lane + 64 * k];

    for (int ii = 0; ii < CI; ++ii) {
        // issue next row's loads before touching this row's data
        float4 rn[4];
        if (ii + 1 < CI) {
            const float4* nrow = rowbase + (size_t)(ii + 1) * (O_ / 4);
#pragma unroll
            for (int k = 0; k < 4; ++k) rn[k] = nrow[lane + 64 * k];
        }

        const float dv = dptr[ii];
        // sigmoid via exp2/rcp: sig = 1/(1+2^(-d*log2e))
        const float sig = fast_rcp(1.0f + fast_exp2(-dv * LOG2E_F));
        const float sigc = sig * LN2_F;
        const float sig2c = sigc * sigc;

        float mr2;
        if (minr2) {
            mr2 = minr2[chunk * CI + ii];
        } else {
            float mn = 3.4e38f;
#pragma unroll
            for (int k = 0; k < 4; ++k)
                mn = fminf(mn, fminf(fminf(r[k].x, r[k].y), fminf(r[k].z, r[k].w)));
#pragma unroll
            for (int off = 32; off > 0; off >>= 1)
                mn = fminf(mn, __shfl_xor(mn, off));
            mr2 = mn;
        }
        const float m2 = fast_rsq(fmaf(mr2, sig2c, EPSC_F)); // exact max, log2 units

        float e[16];
        float z = 0.0f;
#pragma unroll
        for (int k = 0; k < 4; ++k) {
            const float rr[4] = {r[k].x, r[k].y, r[k].z, r[k].w};
#pragma unroll
            for (int j = 0; j < 4; ++j) {
                const float s = fast_rsq(fmaf(rr[j], sig2c, EPSC_F));
                const float ee = fast_exp2(s - m2);          // <= 1
                e[4 * k + j] = ee;
                z += ee;
            }
        }
#pragma unroll
        for (int off = 32; off > 0; off >>= 1)
            z += __shfl_xor(z, off);

        const float scale = dv * fast_rcp(z);                // z >= 1
#pragma unroll
        for (int j = 0; j < 16; ++j) acc[j] = fmaf(e[j], scale, acc[j]);

#pragma unroll
        for (int k = 0; k < 4; ++k) r[k] = rn[k];
    }

    // Stage per-wave accumulators, reduce across the 4 waves in LDS.
#pragma unroll
    for (int k = 0; k < 4; ++k) {
#pragma unroll
        for (int j = 0; j < 4; ++j)
            red[w][4 * lane + 256 * k + j] = acc[4 * k + j];
    }
    __syncthreads();

    const int t = threadIdx.x;       // 0..255, each sums 4 consecutive o's
    float4 v = ((const float4*)red[0])[t];
#pragma unroll
    for (int ww = 1; ww < WPB; ++ww) {
        const float4 u = ((const float4*)red[ww])[t];
        v.x += u.x; v.y += u.y; v.z += u.z; v.w += u.w;
    }
    float* ob = out + b * O_ + 4 * t;
    atomicAdd(&ob[0], v.x);
    atomicAdd(&ob[1], v.y);
    atomicAdd(&ob[2], v.z);
    atomicAdd(&ob[3], v.w);
}

// ---------------------------------------------------------------------------
extern "C" void kernel_launch(void* const* d_in, const int* in_sizes, int n_in,
                              void* d_out, int out_size, void* d_ws, size_t ws_size,
                              hipStream_t stream)
{
    const float* data = (const float*)d_in[0];
    const float* ix   = (const float*)d_in[1];
    const float* iy   = (const float*)d_in[2];
    const float* ox   = (const float*)d_in[3];
    const float* oy   = (const float*)d_in[4];
    const float* la   = (const float*)d_in[5];
    const float* lm   = (const float*)d_in[6];
    float* out  = (float*)d_out;
    float* Tt2  = (float*)d_ws;
    float* minr2 = (ws_size >= TT_BYTES + I_ * sizeof(float))
                       ? (float*)((char*)d_ws + TT_BYTES) : nullptr;

    hipMemsetAsync(d_out, 0, (size_t)B_ * O_ * sizeof(float), stream);

    build_T2_kernel<<<dim3(I_ / 32, O_ / 32), dim3(32, 8), 0, stream>>>(
        ix, iy, ox, oy, la, lm, Tt2);

    if (minr2)
        min_row_kernel<<<I_, 64, 0, stream>>>(Tt2, minr2);

    aeg_main_kernel<<<dim3(NCHUNK / WPB, B_), 256, 0, stream>>>(
        data, Tt2, minr2, out);
}